// Round 5
// baseline (1097.825 us; speedup 1.0000x reference)
//
#include <hip/hip_runtime.h>
#include <hip/hip_bf16.h>

// Head: causal single-head attention fwd. B=8,T=2048,C=H=1024, fp32 in.
// Outputs: out[B,T,H] fp32, wei[B,T,T] fp32 (concat in d_out).
//
// Round 10: R9 post-mortem -> B-direct regressed (unpipelined L2 latency in
// the MFMA dependency chain). R6-R8 all sat at the 2-barrier structural
// ceiling (~614 TF) with <=2 blocks/CU. R10 = m97 configuration: the
// SIMPLEST single-buffered 2-sync loop with SMALL LDS so residency provides
// the overlap:
//   - pv z0 / logits: 32KB single buffer -> 5 blocks/CU (launch_bounds 256,5)
//   - out: 16KB -> ~6-7 blocks/CU
//   - no inline asm, no prefetch slots, no setprio; __syncthreads provides
//     the vmcnt0 drain; cross-block wave overlap fills the stalls.
//   - epilogue stride 136->128 so epilogue reuses the same 32KB (4-way
//     conflicts once per block: negligible).
// Algebra unchanged: M = Wq^T Wk, P = x M (3-pass f16 hi/lo),
// logits = P x^T (3-pass, causal), v 1-pass, out = wei16 @ vT^T.

#define BB 8
#define TT 2048
#define CC 1024
#define HH 1024
#define BT (BB * TT)

typedef _Float16 f16x8 __attribute__((ext_vector_type(8)));
typedef _Float16 f16x4 __attribute__((ext_vector_type(4)));
typedef float f32x4 __attribute__((ext_vector_type(4)));

#define AS1 __attribute__((address_space(1)))
#define AS3 __attribute__((address_space(3)))

__device__ __forceinline__ void gld16(const _Float16* g, _Float16* lds) {
    __builtin_amdgcn_global_load_lds((AS1 const unsigned int*)g,
                                     (AS3 unsigned int*)lds, 16, 0, 0);
}

// ---------------- Kernel 0a: fp32 -> f16 hi/lo split -------------------------
__global__ __launch_bounds__(256) void split_kernel(
    const float* __restrict__ src, _Float16* __restrict__ dh,
    _Float16* __restrict__ dl, int n)
{
    int i = (blockIdx.x * 256 + threadIdx.x) * 4;
    if (i >= n) return;
    float4 v = *(const float4*)(src + i);
    f16x4 h, l;
    h[0] = (_Float16)v.x; l[0] = (_Float16)(v.x - (float)h[0]);
    h[1] = (_Float16)v.y; l[1] = (_Float16)(v.y - (float)h[1]);
    h[2] = (_Float16)v.z; l[2] = (_Float16)(v.z - (float)h[2]);
    h[3] = (_Float16)v.w; l[3] = (_Float16)(v.w - (float)h[3]);
    *(f16x4*)&dh[i] = h;
    *(f16x4*)&dl[i] = l;
}

// ---------------- Kernel 0b: fp32 W[h,c] -> f16 hi/lo W^T[c,h] ---------------
__global__ __launch_bounds__(256) void splitT_kernel(
    const float* __restrict__ W, _Float16* __restrict__ th,
    _Float16* __restrict__ tl)
{
    __shared__ float L[64][65];
    const int h0 = blockIdx.x * 64;
    const int c0 = blockIdx.y * 64;
    const int tid = threadIdx.x;
    {
        const int hl = tid >> 2;
        const int cs = (tid & 3) * 16;
#pragma unroll
        for (int jj = 0; jj < 16; jj += 4) {
            float4 v = *(const float4*)&W[(size_t)(h0 + hl) * CC + c0 + cs + jj];
            L[cs + jj + 0][hl] = v.x;
            L[cs + jj + 1][hl] = v.y;
            L[cs + jj + 2][hl] = v.z;
            L[cs + jj + 3][hl] = v.w;
        }
    }
    __syncthreads();
    const int c  = tid >> 2;
    const int hs = (tid & 3) * 16;
    f16x8 hv0, hv1, lv0, lv1;
#pragma unroll
    for (int i = 0; i < 8; ++i) {
        float a = L[c][hs + i], b = L[c][hs + 8 + i];
        hv0[i] = (_Float16)a; lv0[i] = (_Float16)(a - (float)hv0[i]);
        hv1[i] = (_Float16)b; lv1[i] = (_Float16)(b - (float)hv1[i]);
    }
    size_t o = (size_t)(c0 + c) * HH + h0 + hs;
    *(f16x8*)&th[o] = hv0; *(f16x8*)&th[o + 8] = hv1;
    *(f16x8*)&tl[o] = lv0; *(f16x8*)&tl[o + 8] = lv1;
}

// ---------------- Kernel 1: M^T = (WqT . WkT^T)^T, 3-pass, tiny --------------
__global__ __launch_bounds__(256, 2) void mm_kernel(
    const _Float16* __restrict__ aH, const _Float16* __restrict__ aL,
    const _Float16* __restrict__ bH, const _Float16* __restrict__ bL,
    _Float16* __restrict__ mtH, _Float16* __restrict__ mtL)
{
    __shared__ _Float16 Ah[4096], Al[4096], Bh[4096], Bl[4096];

    const int n0 = blockIdx.x * 128;
    const int m0 = blockIdx.y * 128;

    const int tid  = threadIdx.x;
    const int r0   = tid & 127;
    const int k0   = tid >> 7;
    const int wave = tid >> 6;
    const int lane = tid & 63;
    const int quad = lane >> 4;
    const int lrow = lane & 15;
    const int wr   = (wave >> 1) * 64;
    const int wc   = (wave & 1) * 64;

    const size_t ga = (size_t)(m0 + r0) * HH + k0 * 8;
    const size_t gb = (size_t)(n0 + r0) * HH + k0 * 8;
    const int lds0 = tid * 8, lds1 = (tid + 256) * 8;

    f32x4 acc[4][4] = {};

    for (int kc = 0; kc < HH; kc += 32) {
        __syncthreads();
        gld16(aH + ga + kc,      &Ah[lds0]);
        gld16(aH + ga + kc + 16, &Ah[lds1]);
        gld16(aL + ga + kc,      &Al[lds0]);
        gld16(aL + ga + kc + 16, &Al[lds1]);
        gld16(bH + gb + kc,      &Bh[lds0]);
        gld16(bH + gb + kc + 16, &Bh[lds1]);
        gld16(bL + gb + kc,      &Bl[lds0]);
        gld16(bL + gb + kc + 16, &Bl[lds1]);
        __syncthreads();

        f16x8 ahf[4], alf[4], bhf[4], blf[4];
#pragma unroll
        for (int i = 0; i < 4; ++i) {
            ahf[i] = *(const f16x8*)&Ah[(quad * 128 + wr + i * 16 + lrow) * 8];
            alf[i] = *(const f16x8*)&Al[(quad * 128 + wr + i * 16 + lrow) * 8];
            bhf[i] = *(const f16x8*)&Bh[(quad * 128 + wc + i * 16 + lrow) * 8];
            blf[i] = *(const f16x8*)&Bl[(quad * 128 + wc + i * 16 + lrow) * 8];
        }
#pragma unroll
        for (int i = 0; i < 4; ++i)
#pragma unroll
            for (int j = 0; j < 4; ++j) {
                acc[i][j] = __builtin_amdgcn_mfma_f32_16x16x32_f16(ahf[i], bhf[j], acc[i][j], 0, 0, 0);
                acc[i][j] = __builtin_amdgcn_mfma_f32_16x16x32_f16(ahf[i], blf[j], acc[i][j], 0, 0, 0);
                acc[i][j] = __builtin_amdgcn_mfma_f32_16x16x32_f16(alf[i], bhf[j], acc[i][j], 0, 0, 0);
            }
    }

    // write transposed: MT[n][m], 4 consecutive m per lane -> f16x4
#pragma unroll
    for (int i = 0; i < 4; ++i)
#pragma unroll
        for (int j = 0; j < 4; ++j) {
            int mm = m0 + wr + i * 16 + quad * 4;
            int nn = n0 + wc + j * 16 + lrow;
            f16x4 ph, pl;
#pragma unroll
            for (int r = 0; r < 4; ++r) {
                float val = acc[i][j][r];
                _Float16 h = (_Float16)val;
                ph[r] = h;
                pl[r] = (_Float16)(val - (float)h);
            }
            *(f16x4*)&mtH[(size_t)nn * CC + mm] = ph;
            *(f16x4*)&mtL[(size_t)nn * CC + mm] = pl;
        }
}

// ---------------- Kernel 2: fused P = x M (3-pass) and v = x Wv^T (1-pass) ---
// m97-structure: 32KB single buffer, 2 syncs/iter, 5 blocks/CU.
#define EPI_STRIDE 128
__global__ __launch_bounds__(256, 5) void pv_kernel(
    const _Float16* __restrict__ xh, const _Float16* __restrict__ xl,
    const _Float16* __restrict__ mtH, const _Float16* __restrict__ mtL,
    const _Float16* __restrict__ Wvh,
    _Float16* __restrict__ Ph, _Float16* __restrict__ Pl,
    _Float16* __restrict__ vT)
{
    __shared__ _Float16 S[16384];   // 32KB: staging + epilogue (128x128)

    const int idx   = blockIdx.x;
    const int z     = idx >> 10;               // 0: P, 1: v
    const int r     = idx & 1023;
    const int xcd   = r & 7;
    const int j7    = r >> 3;                  // 0..127
    const int mtile = xcd * 16 + (j7 >> 3);    // 0..127
    const int ntile = j7 & 7;                  // 0..7
    const int m0 = mtile * 128;
    const int n0 = ntile * 128;

    const int tid  = threadIdx.x;
    const int r0   = tid & 127;
    const int k0   = tid >> 7;
    const int wave = tid >> 6;
    const int lane = tid & 63;
    const int quad = lane >> 4;
    const int lrow = lane & 15;
    const int wr   = (wave >> 1) * 64;
    const int wc   = (wave & 1) * 64;

    const size_t ga = (size_t)(m0 + r0) * CC + k0 * 8;
    const size_t gb = (size_t)(n0 + r0) * CC + k0 * 8;
    const int lds0 = tid * 8, lds1 = (tid + 256) * 8;

    f32x4 acc[4][4] = {};

    if (z == 0) {
        for (int kc = 0; kc < CC; kc += 32) {
            __syncthreads();
            gld16(xh  + ga + kc,      &S[lds0]);
            gld16(xh  + ga + kc + 16, &S[lds1]);
            gld16(xl  + ga + kc,      &S[4096 + lds0]);
            gld16(xl  + ga + kc + 16, &S[4096 + lds1]);
            gld16(mtH + gb + kc,      &S[8192 + lds0]);
            gld16(mtH + gb + kc + 16, &S[8192 + lds1]);
            gld16(mtL + gb + kc,      &S[12288 + lds0]);
            gld16(mtL + gb + kc + 16, &S[12288 + lds1]);
            __syncthreads();

            f16x8 ahf[4], alf[4], bhf[4], blf[4];
#pragma unroll
            for (int i = 0; i < 4; ++i) {
                ahf[i] = *(const f16x8*)&S[(quad * 128 + wr + i * 16 + lrow) * 8];
                alf[i] = *(const f16x8*)&S[4096 + (quad * 128 + wr + i * 16 + lrow) * 8];
                bhf[i] = *(const f16x8*)&S[8192 + (quad * 128 + wc + i * 16 + lrow) * 8];
                blf[i] = *(const f16x8*)&S[12288 + (quad * 128 + wc + i * 16 + lrow) * 8];
            }
#pragma unroll
            for (int i = 0; i < 4; ++i)
#pragma unroll
                for (int j = 0; j < 4; ++j) {
                    acc[i][j] = __builtin_amdgcn_mfma_f32_16x16x32_f16(ahf[i], bhf[j], acc[i][j], 0, 0, 0);
                    acc[i][j] = __builtin_amdgcn_mfma_f32_16x16x32_f16(ahf[i], blf[j], acc[i][j], 0, 0, 0);
                    acc[i][j] = __builtin_amdgcn_mfma_f32_16x16x32_f16(alf[i], bhf[j], acc[i][j], 0, 0, 0);
                }
        }
    } else {
        for (int kc = 0; kc < CC; kc += 32) {
            __syncthreads();
            gld16(xh  + ga + kc,      &S[lds0]);
            gld16(xh  + ga + kc + 16, &S[lds1]);
            gld16(Wvh + gb + kc,      &S[4096 + lds0]);
            gld16(Wvh + gb + kc + 16, &S[4096 + lds1]);
            __syncthreads();

            f16x8 ahf[4], bhf[4];
#pragma unroll
            for (int i = 0; i < 4; ++i) {
                ahf[i] = *(const f16x8*)&S[(quad * 128 + wr + i * 16 + lrow) * 8];
                bhf[i] = *(const f16x8*)&S[4096 + (quad * 128 + wc + i * 16 + lrow) * 8];
            }
#pragma unroll
            for (int i = 0; i < 4; ++i)
#pragma unroll
                for (int j = 0; j < 4; ++j)
                    acc[i][j] = __builtin_amdgcn_mfma_f32_16x16x32_f16(ahf[i], bhf[j], acc[i][j], 0, 0, 0);
        }
    }

    __syncthreads();

    if (z == 1) {
        // stage vT tile [h_local][t_local] in LDS, then coalesced f16x8 stores
#pragma unroll
        for (int i = 0; i < 4; ++i)
#pragma unroll
            for (int j = 0; j < 4; ++j) {
                int hl = wc + j * 16 + lrow;
                int tl = wr + i * 16 + quad * 4;
                f16x4 p;
#pragma unroll
                for (int rr = 0; rr < 4; ++rr) p[rr] = (_Float16)acc[i][j][rr];
                *(f16x4*)&S[hl * EPI_STRIDE + tl] = p;
            }
        __syncthreads();
        const int bi  = mtile >> 4;            // batch of this m-strip
        const int t0g = (mtile & 15) * 128;
        _Float16* vb = vT + (size_t)bi * HH * TT;
#pragma unroll
        for (int rr = 0; rr < 128; rr += 16) {
            int h = rr + (tid >> 4);
            int t = (tid & 15) * 8;
            f16x8 val = *(const f16x8*)&S[h * EPI_STRIDE + t];
            *(f16x8*)&vb[(size_t)(n0 + h) * TT + t0g + t] = val;
        }
    } else {
        // pass 1: hi tile staged [t_local][c_local], coalesced store
#pragma unroll
        for (int i = 0; i < 4; ++i)
#pragma unroll
            for (int j = 0; j < 4; ++j) {
                int tl = wr + i * 16 + quad * 4;
                int cl = wc + j * 16 + lrow;
#pragma unroll
                for (int rr = 0; rr < 4; ++rr)
                    S[(tl + rr) * EPI_STRIDE + cl] = (_Float16)acc[i][j][rr];
            }
        __syncthreads();
#pragma unroll
        for (int rr = 0; rr < 128; rr += 16) {
            int t = rr + (tid >> 4);
            int c = (tid & 15) * 8;
            f16x8 val = *(const f16x8*)&S[t * EPI_STRIDE + c];
            *(f16x8*)&Ph[(size_t)(m0 + t) * CC + n0 + c] = val;
        }
        // pass 2: lo tile
        __syncthreads();
#pragma unroll
        for (int i = 0; i < 4; ++i)
#pragma unroll
            for (int j = 0; j < 4; ++j) {
                int tl = wr + i * 16 + quad * 4;
                int cl = wc + j * 16 + lrow;
#pragma unroll
                for (int rr = 0; rr < 4; ++rr) {
                    float val = acc[i][j][rr];
                    _Float16 h = (_Float16)val;
                    S[(tl + rr) * EPI_STRIDE + cl] = (_Float16)(val - (float)h);
                }
            }
        __syncthreads();
#pragma unroll
        for (int rr = 0; rr < 128; rr += 16) {
            int t = rr + (tid >> 4);
            int c = (tid & 15) * 8;
            f16x8 val = *(const f16x8*)&S[t * EPI_STRIDE + c];
            *(f16x8*)&Pl[(size_t)(m0 + t) * CC + n0 + c] = val;
        }
    }
}

// ---------------- Kernel 3: wei = (P x^T)/32, lower-tri 128-tiles, 3-pass ----
// Compact 1-D grid: 136 tri-tiles x 8 batches; batch == XCD strip.
// m97-structure: 32KB single buffer, 5 blocks/CU.
__global__ __launch_bounds__(256, 5) void logits_kernel(
    const _Float16* __restrict__ Ph, const _Float16* __restrict__ Pl,
    const _Float16* __restrict__ xh, const _Float16* __restrict__ xl,
    float* __restrict__ wei)
{
    __shared__ _Float16 S[16384];   // 32KB single buffer

    const int id  = blockIdx.x;
    const int b   = id & 7;          // batch == XCD
    const int tri = id >> 3;         // 0..135, row-major lower triangle
    int tt = (int)((sqrtf(8.0f * (float)tri + 1.0f) - 1.0f) * 0.5f);
    while ((tt + 1) * (tt + 2) / 2 <= tri) ++tt;
    while (tt * (tt + 1) / 2 > tri) --tt;
    const int st = tri - tt * (tt + 1) / 2;

    const size_t base = (size_t)b * TT * CC;
    float* wb = wei + (size_t)b * TT * TT;
    const int m0 = tt * 128;
    const int n0 = st * 128;

    const int tid  = threadIdx.x;
    const int r0   = tid & 127;
    const int k0   = tid >> 7;
    const int wave = tid >> 6;
    const int lane = tid & 63;
    const int quad = lane >> 4;
    const int lrow = lane & 15;
    const int wr   = (wave >> 1) * 64;
    const int wc   = (wave & 1) * 64;

    const size_t ga = base + (size_t)(m0 + r0) * CC + k0 * 8;
    const size_t gb = base + (size_t)(n0 + r0) * CC + k0 * 8;
    const int lds0 = tid * 8, lds1 = (tid + 256) * 8;

    f32x4 acc[4][4] = {};

    for (int kc = 0; kc < CC; kc += 32) {
        __syncthreads();
        gld16(Ph + ga + kc,      &S[lds0]);
        gld16(Ph + ga + kc + 16, &S[lds1]);
        gld16(Pl + ga + kc,      &S[4096 + lds0]);
        gld16(Pl + ga + kc + 16, &S[4096 + lds1]);
        gld16(xh + gb + kc,      &S[8192 + lds0]);
        gld16(xh + gb + kc + 16, &S[8192 + lds1]);
        gld16(xl + gb + kc,      &S[12288 + lds0]);
        gld16(xl + gb + kc + 16, &S[12288 + lds1]);
        __syncthreads();

        f16x8 ahf[4], alf[4], bhf[4], blf[4];
#pragma unroll
        for (int i = 0; i < 4; ++i) {
            ahf[i] = *(const f16x8*)&S[(quad * 128 + wr + i * 16 + lrow) * 8];
            alf[i] = *(const f16x8*)&S[4096 + (quad * 128 + wr + i * 16 + lrow) * 8];
            bhf[i] = *(const f16x8*)&S[8192 + (quad * 128 + wc + i * 16 + lrow) * 8];
            blf[i] = *(const f16x8*)&S[12288 + (quad * 128 + wc + i * 16 + lrow) * 8];
        }
#pragma unroll
        for (int i = 0; i < 4; ++i)
#pragma unroll
            for (int j = 0; j < 4; ++j) {
                acc[i][j] = __builtin_amdgcn_mfma_f32_16x16x32_f16(ahf[i], bhf[j], acc[i][j], 0, 0, 0);
                acc[i][j] = __builtin_amdgcn_mfma_f32_16x16x32_f16(ahf[i], blf[j], acc[i][j], 0, 0, 0);
                acc[i][j] = __builtin_amdgcn_mfma_f32_16x16x32_f16(alf[i], bhf[j], acc[i][j], 0, 0, 0);
            }
    }

    const float scale = 0.03125f;   // 1024^-0.5
#pragma unroll
    for (int i = 0; i < 4; ++i)
#pragma unroll
        for (int j = 0; j < 4; ++j)
#pragma unroll
            for (int r = 0; r < 4; ++r) {
                int rr = wr + i * 16 + quad * 4 + r;
                int cc = wc + j * 16 + lrow;
                wb[(size_t)(m0 + rr) * TT + n0 + cc] = acc[i][j][r] * scale;
            }
}

// ---------------- Kernel 4: causal softmax; writes fp32 wei + f16 wei16 ------
__global__ __launch_bounds__(256) void softmax_kernel(
    float* __restrict__ wei, _Float16* __restrict__ wei16)
{
    const int t = blockIdx.x;
    const int b = blockIdx.y;
    float* row = wei + (size_t)b * TT * TT + (size_t)t * TT;
    _Float16* row16 = wei16 + (size_t)b * TT * TT + (size_t)t * TT;
    const int n = t + 1;
    const int tid = threadIdx.x;
    const int base = tid * 8;

    float vals[8];
    if (base < n) {
        float4 v0 = *(const float4*)&row[base];
        float4 v1 = *(const float4*)&row[base + 4];
        vals[0] = v0.x; vals[1] = v0.y; vals[2] = v0.z; vals[3] = v0.w;
        vals[4] = v1.x; vals[5] = v1.y; vals[6] = v1.z; vals[7] = v1.w;
    } else {
#pragma unroll
        for (int i = 0; i < 8; ++i) vals[i] = -INFINITY;
    }

    float mx = -INFINITY;
#pragma unroll
    for (int i = 0; i < 8; ++i) {
        if (base + i >= n) vals[i] = -INFINITY;
        mx = fmaxf(mx, vals[i]);
    }
#pragma unroll
    for (int off = 32; off > 0; off >>= 1)
        mx = fmaxf(mx, __shfl_down(mx, off));

    __shared__ float redm[4];
    __shared__ float reds[4];
    if ((tid & 63) == 0) redm[tid >> 6] = mx;
    __syncthreads();
    const float m = fmaxf(fmaxf(redm[0], redm[1]), fmaxf(redm[2], redm[3]));

    float sum = 0.f;
#pragma unroll
    for (int i = 0; i < 8; ++i) {
        vals[i] = __expf(vals[i] - m);
        sum += vals[i];
    }
#pragma unroll
    for (int off = 32; off > 0; off >>= 1)
        sum += __shfl_down(sum, off);
    if ((tid & 63) == 0) reds[tid >> 6] = sum;
    __syncthreads();
    const float inv = 1.0f / (reds[0] + reds[1] + reds[2] + reds[3]);

    f16x8 h;
#pragma unroll
    for (int i = 0; i < 8; ++i) {
        float w = vals[i] * inv;     // masked: exp(-inf)*inv = 0 exactly
        vals[i] = w;
        h[i] = (_Float16)w;
    }
    *(float4*)&row[base]     = make_float4(vals[0], vals[1], vals[2], vals[3]);
    *(float4*)&row[base + 4] = make_float4(vals[4], vals[5], vals[6], vals[7]);
    *(f16x8*)&row16[base]    = h;
}

// ---------------- Kernel 5: out = wei16 @ vT^T (NT, f16, causal K) -----------
// Compact 1-D grid: batch == XCD strip, heavy (large tt) tiles first.
// m97-structure: 16KB single buffer, ~6-7 blocks/CU.
__global__ __launch_bounds__(256, 4) void out_kernel(
    const _Float16* __restrict__ wei16, const _Float16* __restrict__ vT,
    float* __restrict__ out)
{
    __shared__ _Float16 S[8192];    // 16KB single buffer

    const int id = blockIdx.x;
    const int b  = id & 7;          // batch == XCD
    const int r  = id >> 3;         // 0..127
    const int tt = 15 - (r >> 3);   // heavy tiles dispatched first
    const int nb = r & 7;

    const _Float16* wb = wei16 + (size_t)b * TT * TT;
    const _Float16* vb = vT    + (size_t)b * HH * TT;
    float*          ob = out   + (size_t)b * TT * HH;

    const int m0 = tt * 128;
    const int n0 = nb * 128;
    const int kend = (tt + 1) * 128;  // wei16==0 above diagonal

    const int tid  = threadIdx.x;
    const int r0   = tid & 127;
    const int k0   = tid >> 7;
    const int wave = tid >> 6;
    const int lane = tid & 63;
    const int quad = lane >> 4;
    const int lrow = lane & 15;
    const int wr   = (wave >> 1) * 64;
    const int wc   = (wave & 1) * 64;

    const size_t ga = (size_t)(m0 + r0) * TT + k0 * 8;
    const size_t gb = (size_t)(n0 + r0) * TT + k0 * 8;
    const int lds0 = tid * 8, lds1 = (tid + 256) * 8;

    f32x4 acc[4][4] = {};

    for (int kc = 0; kc < kend; kc += 32) {
        __syncthreads();
        gld16(wb + ga + kc,      &S[lds0]);
        gld16(wb + ga + kc + 16, &S[lds1]);
        gld16(vb + gb + kc,      &S[4096 + lds0]);
        gld16(vb + gb + kc + 16, &S[4096 + lds1]);
        __syncthreads();

        f16x8 ahf[4], bhf[4];
#pragma unroll
        for (int i = 0; i < 4; ++i) {
            ahf[i] = *(const f16x8*)&S[(quad * 128 + wr + i * 16 + lrow) * 8];
            bhf[i] = *(const f16x8*)&S[4096 + (quad * 128 + wc + i * 16 + lrow) * 8];
        }
#pragma unroll
        for (int i = 0; i < 4; ++i)
#pragma unroll
            for (int j = 0; j < 4; ++j)
                acc[i][j] = __builtin_amdgcn_mfma_f32_16x16x32_f16(ahf[i], bhf[j], acc[i][j], 0, 0, 0);
    }

#pragma unroll
    for (int i = 0; i < 4; ++i)
#pragma unroll
        for (int j = 0; j < 4; ++j)
#pragma unroll
            for (int r2 = 0; r2 < 4; ++r2) {
                int rr = wr + i * 16 + quad * 4 + r2;
                int cc = wc + j * 16 + lrow;
                ob[(size_t)(m0 + rr) * HH + n0 + cc] = acc[i][j][r2];
            }
}

extern "C" void kernel_launch(void* const* d_in, const int* in_sizes, int n_in,
                              void* d_out, int out_size, void* d_ws, size_t ws_size,
                              hipStream_t stream)
{
    const float* x  = (const float*)d_in[0];
    const float* Wk = (const float*)d_in[1];
    const float* Wq = (const float*)d_in[2];
    const float* Wv = (const float*)d_in[3];

    const size_t NX = (size_t)BT * CC;          // 16M
    const size_t NW = (size_t)HH * CC;          // 1M

    float* out = (float*)d_out;                 // [8,2048,1024] fp32
    float* wei = out + (size_t)BT * HH;         // [8,2048,2048] fp32

    // W-derived scratch in d_out's OUT region (64MB; dead before out_kernel)
    _Float16* WqTh = (_Float16*)out;            // [C,H]
    _Float16* WqTl = WqTh + NW;
    _Float16* WkTh = WqTl + NW;
    _Float16* WkTl = WkTh + NW;
    _Float16* Wvh  = WkTl + NW;                 // [H,C]
    _Float16* Wvl  = Wvh  + NW;                 // scratch (unused)
    _Float16* MTh  = Wvl  + NW;                 // [C,C] = M^T
    _Float16* MTl  = MTh  + NW;                 // total 16MB < 64MB

    // ws: 160MB = 5 x 32MB
    _Float16* xh = (_Float16*)d_ws;
    _Float16* xl = xh + NX;
    _Float16* Ph = xl + NX;
    _Float16* Pl = Ph + NX;
    _Float16* vT = Pl + NX;                     // [B][H][T]
    _Float16* wei16 = (_Float16*)d_ws;          // overlays xh/xl/Ph after logits

    split_kernel<<<dim3(NX / 1024), 256, 0, stream>>>(x, xh, xl, (int)NX);
    splitT_kernel<<<dim3(HH / 64, CC / 64), 256, 0, stream>>>(Wq, WqTh, WqTl);
    splitT_kernel<<<dim3(HH / 64, CC / 64), 256, 0, stream>>>(Wk, WkTh, WkTl);
    split_kernel<<<dim3(NW / 1024), 256, 0, stream>>>(Wv, Wvh, Wvl, (int)NW);

    mm_kernel<<<dim3(CC / 128, CC / 128), 256, 0, stream>>>(
        WqTh, WqTl, WkTh, WkTl, MTh, MTl);
    pv_kernel<<<dim3(2048), 256, 0, stream>>>(
        xh, xl, MTh, MTl, Wvh, Ph, Pl, vT);
    logits_kernel<<<dim3(136 * BB), 256, 0, stream>>>(
        Ph, Pl, xh, xl, wei);
    softmax_kernel<<<dim3(TT, BB), 256, 0, stream>>>(wei, wei16);
    out_kernel<<<dim3(128 * BB), 256, 0, stream>>>(wei16, vT, out);
}

// Round 6
// 796.914 us; speedup vs baseline: 1.3776x; 1.3776x over previous
//
#include <hip/hip_runtime.h>
#include <hip/hip_bf16.h>

// Head: causal single-head attention fwd. B=8,T=2048,C=H=1024, fp32 in.
// Outputs: out[B,T,H] fp32, wei[B,T,T] fp32 (concat in d_out).
//
// Round 11: consolidate to R8 (best measured: 800.8us). R9 (B-direct) and
// R10 (5 blk/CU) both regressed; R10's counters showed L2 thrash (WRITE
// 98->452MB, HBM-bound). R8 = asymmetric-depth counted-vmcnt pipeline at
// 2 blocks/CU:
//   - A-stream (x / P strips): depth-3. B-stream (M / x): depth-2.
//   - LDS 80KB -> 2 blocks/CU; per iter: vmcnt(4) completes A(k)+B(k);
//     issue B(k+1) then A(k+2); one s_barrier/iter.
//   - pv z1: pure depth-3 (2 streams). out: depth-3 48KB, 3 blocks/CU.
//   Delta vs R8: s_setprio removed (m190: null-to-negative for lockstep
//   barrier GEMMs; setprio only pays with wave role-split).
// Algebra unchanged: M = Wq^T Wk, P = x M (3-pass f16 hi/lo),
// logits = P x^T (3-pass, causal), v 1-pass, out = wei16 @ vT^T.

#define BB 8
#define TT 2048
#define CC 1024
#define HH 1024
#define BT (BB * TT)

typedef _Float16 f16x8 __attribute__((ext_vector_type(8)));
typedef _Float16 f16x4 __attribute__((ext_vector_type(4)));
typedef float f32x4 __attribute__((ext_vector_type(4)));

#define AS1 __attribute__((address_space(1)))
#define AS3 __attribute__((address_space(3)))

__device__ __forceinline__ void gld16(const _Float16* g, _Float16* lds) {
    __builtin_amdgcn_global_load_lds((AS1 const unsigned int*)g,
                                     (AS3 unsigned int*)lds, 16, 0, 0);
}

// ---------------- Kernel 0a: fp32 -> f16 hi/lo split -------------------------
__global__ __launch_bounds__(256) void split_kernel(
    const float* __restrict__ src, _Float16* __restrict__ dh,
    _Float16* __restrict__ dl, int n)
{
    int i = (blockIdx.x * 256 + threadIdx.x) * 4;
    if (i >= n) return;
    float4 v = *(const float4*)(src + i);
    f16x4 h, l;
    h[0] = (_Float16)v.x; l[0] = (_Float16)(v.x - (float)h[0]);
    h[1] = (_Float16)v.y; l[1] = (_Float16)(v.y - (float)h[1]);
    h[2] = (_Float16)v.z; l[2] = (_Float16)(v.z - (float)h[2]);
    h[3] = (_Float16)v.w; l[3] = (_Float16)(v.w - (float)h[3]);
    *(f16x4*)&dh[i] = h;
    *(f16x4*)&dl[i] = l;
}

// ---------------- Kernel 0b: fp32 W[h,c] -> f16 hi/lo W^T[c,h] ---------------
__global__ __launch_bounds__(256) void splitT_kernel(
    const float* __restrict__ W, _Float16* __restrict__ th,
    _Float16* __restrict__ tl)
{
    __shared__ float L[64][65];
    const int h0 = blockIdx.x * 64;
    const int c0 = blockIdx.y * 64;
    const int tid = threadIdx.x;
    {
        const int hl = tid >> 2;
        const int cs = (tid & 3) * 16;
#pragma unroll
        for (int jj = 0; jj < 16; jj += 4) {
            float4 v = *(const float4*)&W[(size_t)(h0 + hl) * CC + c0 + cs + jj];
            L[cs + jj + 0][hl] = v.x;
            L[cs + jj + 1][hl] = v.y;
            L[cs + jj + 2][hl] = v.z;
            L[cs + jj + 3][hl] = v.w;
        }
    }
    __syncthreads();
    const int c  = tid >> 2;
    const int hs = (tid & 3) * 16;
    f16x8 hv0, hv1, lv0, lv1;
#pragma unroll
    for (int i = 0; i < 8; ++i) {
        float a = L[c][hs + i], b = L[c][hs + 8 + i];
        hv0[i] = (_Float16)a; lv0[i] = (_Float16)(a - (float)hv0[i]);
        hv1[i] = (_Float16)b; lv1[i] = (_Float16)(b - (float)hv1[i]);
    }
    size_t o = (size_t)(c0 + c) * HH + h0 + hs;
    *(f16x8*)&th[o] = hv0; *(f16x8*)&th[o + 8] = hv1;
    *(f16x8*)&tl[o] = lv0; *(f16x8*)&tl[o + 8] = lv1;
}

// ---------------- Kernel 1: M^T = (WqT . WkT^T)^T, 3-pass, tiny --------------
__global__ __launch_bounds__(256, 2) void mm_kernel(
    const _Float16* __restrict__ aH, const _Float16* __restrict__ aL,
    const _Float16* __restrict__ bH, const _Float16* __restrict__ bL,
    _Float16* __restrict__ mtH, _Float16* __restrict__ mtL)
{
    __shared__ _Float16 Ah[4096], Al[4096], Bh[4096], Bl[4096];

    const int n0 = blockIdx.x * 128;
    const int m0 = blockIdx.y * 128;

    const int tid  = threadIdx.x;
    const int r0   = tid & 127;
    const int k0   = tid >> 7;
    const int wave = tid >> 6;
    const int lane = tid & 63;
    const int quad = lane >> 4;
    const int lrow = lane & 15;
    const int wr   = (wave >> 1) * 64;
    const int wc   = (wave & 1) * 64;

    const size_t ga = (size_t)(m0 + r0) * HH + k0 * 8;
    const size_t gb = (size_t)(n0 + r0) * HH + k0 * 8;
    const int lds0 = tid * 8, lds1 = (tid + 256) * 8;

    f32x4 acc[4][4] = {};

    for (int kc = 0; kc < HH; kc += 32) {
        __syncthreads();
        gld16(aH + ga + kc,      &Ah[lds0]);
        gld16(aH + ga + kc + 16, &Ah[lds1]);
        gld16(aL + ga + kc,      &Al[lds0]);
        gld16(aL + ga + kc + 16, &Al[lds1]);
        gld16(bH + gb + kc,      &Bh[lds0]);
        gld16(bH + gb + kc + 16, &Bh[lds1]);
        gld16(bL + gb + kc,      &Bl[lds0]);
        gld16(bL + gb + kc + 16, &Bl[lds1]);
        __syncthreads();

        f16x8 ahf[4], alf[4], bhf[4], blf[4];
#pragma unroll
        for (int i = 0; i < 4; ++i) {
            ahf[i] = *(const f16x8*)&Ah[(quad * 128 + wr + i * 16 + lrow) * 8];
            alf[i] = *(const f16x8*)&Al[(quad * 128 + wr + i * 16 + lrow) * 8];
            bhf[i] = *(const f16x8*)&Bh[(quad * 128 + wc + i * 16 + lrow) * 8];
            blf[i] = *(const f16x8*)&Bl[(quad * 128 + wc + i * 16 + lrow) * 8];
        }
#pragma unroll
        for (int i = 0; i < 4; ++i)
#pragma unroll
            for (int j = 0; j < 4; ++j) {
                acc[i][j] = __builtin_amdgcn_mfma_f32_16x16x32_f16(ahf[i], bhf[j], acc[i][j], 0, 0, 0);
                acc[i][j] = __builtin_amdgcn_mfma_f32_16x16x32_f16(ahf[i], blf[j], acc[i][j], 0, 0, 0);
                acc[i][j] = __builtin_amdgcn_mfma_f32_16x16x32_f16(alf[i], bhf[j], acc[i][j], 0, 0, 0);
            }
    }

    // write transposed: MT[n][m], 4 consecutive m per lane -> f16x4
#pragma unroll
    for (int i = 0; i < 4; ++i)
#pragma unroll
        for (int j = 0; j < 4; ++j) {
            int mm = m0 + wr + i * 16 + quad * 4;
            int nn = n0 + wc + j * 16 + lrow;
            f16x4 ph, pl;
#pragma unroll
            for (int r = 0; r < 4; ++r) {
                float val = acc[i][j][r];
                _Float16 h = (_Float16)val;
                ph[r] = h;
                pl[r] = (_Float16)(val - (float)h);
            }
            *(f16x4*)&mtH[(size_t)nn * CC + mm] = ph;
            *(f16x4*)&mtL[(size_t)nn * CC + mm] = pl;
        }
}

// ---------------- Kernel 2: fused P = x M (3-pass) and v = x Wv^T (1-pass) ---
// 1-D grid 2048, XCD-strip swizzle; asymmetric-depth counted-vmcnt pipeline
// (A depth-3, B depth-2; 80KB -> 2 blocks/CU); LDS-staged coalesced epilogues.
#define EPI_STRIDE 136   // 128 + 8 pad
__global__ __launch_bounds__(256, 2) void pv_kernel(
    const _Float16* __restrict__ xh, const _Float16* __restrict__ xl,
    const _Float16* __restrict__ mtH, const _Float16* __restrict__ mtL,
    const _Float16* __restrict__ Wvh,
    _Float16* __restrict__ Ph, _Float16* __restrict__ Pl,
    _Float16* __restrict__ vT)
{
    // z0: A slots 3 x 8192 f16 @0, B slots 2 x 8192 f16 @24576 -> 80KB
    // z1: slots 3 x 8192 f16 @0 (xh|Wvh)
    __shared__ _Float16 S[40960];

    const int idx   = blockIdx.x;
    const int z     = idx >> 10;               // 0: P, 1: v
    const int r     = idx & 1023;
    const int xcd   = r & 7;
    const int j7    = r >> 3;                  // 0..127
    const int mtile = xcd * 16 + (j7 >> 3);    // 0..127
    const int ntile = j7 & 7;                  // 0..7
    const int m0 = mtile * 128;
    const int n0 = ntile * 128;

    const int tid  = threadIdx.x;
    const int r0   = tid & 127;
    const int k0   = tid >> 7;
    const int wave = tid >> 6;
    const int lane = tid & 63;
    const int quad = lane >> 4;
    const int lrow = lane & 15;
    const int wr   = (wave >> 1) * 64;
    const int wc   = (wave & 1) * 64;

    const size_t ga = (size_t)(m0 + r0) * CC + k0 * 8;
    const size_t gb = (size_t)(n0 + r0) * CC + k0 * 8;
    const int lds0 = tid * 8, lds1 = (tid + 256) * 8;

    f32x4 acc[4][4] = {};

    if (z == 0) {
#define PV_A(kc_, sp_) do { \
        _Float16* Sb = S + (sp_) * 8192; \
        gld16(xh + ga + (kc_),      &Sb[lds0]); \
        gld16(xh + ga + (kc_) + 16, &Sb[lds1]); \
        gld16(xl + ga + (kc_),      &Sb[4096 + lds0]); \
        gld16(xl + ga + (kc_) + 16, &Sb[4096 + lds1]); \
    } while (0)
#define PV_B(kc_, sp_) do { \
        _Float16* Sb = S + 24576 + (sp_) * 8192; \
        gld16(mtH + gb + (kc_),      &Sb[lds0]); \
        gld16(mtH + gb + (kc_) + 16, &Sb[lds1]); \
        gld16(mtL + gb + (kc_),      &Sb[4096 + lds0]); \
        gld16(mtL + gb + (kc_) + 16, &Sb[4096 + lds1]); \
    } while (0)
        // prologue order matters for vmcnt: A0, B0, A1 (12 instrs)
        PV_A(0, 0);
        PV_B(0, 0);
        PV_A(32, 1);
        int sa = 0, sb = 0;
        for (int kc = 0; kc < CC; kc += 32) {
            // completes A(k)+B(k) (8 oldest of 12), leaves A(k+1)
            asm volatile("s_waitcnt vmcnt(4)" ::: "memory");
            __builtin_amdgcn_s_barrier();
            __builtin_amdgcn_sched_barrier(0);

            // issue B(k+1) first, then A(k+2) (keeps vmcnt(4) invariant)
            int kb = kc + 32; if (kb > CC - 32) kb = CC - 32;
            PV_B(kb, sb ^ 1);
            int ka = kc + 64; if (ka > CC - 32) ka = CC - 32;
            int s2 = sa + 2; if (s2 >= 3) s2 -= 3;
            PV_A(ka, s2);

            const _Float16* Ah = S + sa * 8192;
            const _Float16* Al = Ah + 4096;
            const _Float16* Bh = S + 24576 + sb * 8192;
            const _Float16* Bl = Bh + 4096;

            f16x8 ahf[4], alf[4], bhf[4], blf[4];
#pragma unroll
            for (int i = 0; i < 4; ++i) {
                ahf[i] = *(const f16x8*)&Ah[(quad * 128 + wr + i * 16 + lrow) * 8];
                alf[i] = *(const f16x8*)&Al[(quad * 128 + wr + i * 16 + lrow) * 8];
                bhf[i] = *(const f16x8*)&Bh[(quad * 128 + wc + i * 16 + lrow) * 8];
                blf[i] = *(const f16x8*)&Bl[(quad * 128 + wc + i * 16 + lrow) * 8];
            }
#pragma unroll
            for (int i = 0; i < 4; ++i)
#pragma unroll
                for (int j = 0; j < 4; ++j) {
                    acc[i][j] = __builtin_amdgcn_mfma_f32_16x16x32_f16(ahf[i], bhf[j], acc[i][j], 0, 0, 0);
                    acc[i][j] = __builtin_amdgcn_mfma_f32_16x16x32_f16(ahf[i], blf[j], acc[i][j], 0, 0, 0);
                    acc[i][j] = __builtin_amdgcn_mfma_f32_16x16x32_f16(alf[i], bhf[j], acc[i][j], 0, 0, 0);
                }

            ++sa; if (sa == 3) sa = 0;
            sb ^= 1;
        }
    } else {
#define PV_S1(kc_, sp_) do { \
        _Float16* Sb = S + (sp_) * 8192; \
        gld16(xh  + ga + (kc_),      &Sb[lds0]); \
        gld16(xh  + ga + (kc_) + 16, &Sb[lds1]); \
        gld16(Wvh + gb + (kc_),      &Sb[4096 + lds0]); \
        gld16(Wvh + gb + (kc_) + 16, &Sb[4096 + lds1]); \
    } while (0)
        PV_S1(0, 0);
        PV_S1(32, 1);
        int sl = 0;
        for (int kc = 0; kc < CC; kc += 32) {
            asm volatile("s_waitcnt vmcnt(4)" ::: "memory");
            __builtin_amdgcn_s_barrier();
            __builtin_amdgcn_sched_barrier(0);

            int kpre = kc + 64;
            if (kpre > CC - 32) kpre = CC - 32;
            int s2 = sl + 2; if (s2 >= 3) s2 -= 3;
            PV_S1(kpre, s2);

            const _Float16* Ah = S + sl * 8192;
            const _Float16* Bh = Ah + 4096;

            f16x8 ahf[4], bhf[4];
#pragma unroll
            for (int i = 0; i < 4; ++i) {
                ahf[i] = *(const f16x8*)&Ah[(quad * 128 + wr + i * 16 + lrow) * 8];
                bhf[i] = *(const f16x8*)&Bh[(quad * 128 + wc + i * 16 + lrow) * 8];
            }
#pragma unroll
            for (int i = 0; i < 4; ++i)
#pragma unroll
                for (int j = 0; j < 4; ++j)
                    acc[i][j] = __builtin_amdgcn_mfma_f32_16x16x32_f16(ahf[i], bhf[j], acc[i][j], 0, 0, 0);

            ++sl; if (sl == 3) sl = 0;
        }
    }

    // drain in-flight (garbage) prefetches before reusing LDS / kernel end
    asm volatile("s_waitcnt vmcnt(0)" ::: "memory");
    __syncthreads();

    if (z == 1) {
        // stage vT tile [h_local][t_local] in LDS, then coalesced f16x8 stores
#pragma unroll
        for (int i = 0; i < 4; ++i)
#pragma unroll
            for (int j = 0; j < 4; ++j) {
                int hl = wc + j * 16 + lrow;
                int tl = wr + i * 16 + quad * 4;
                f16x4 p;
#pragma unroll
                for (int rr = 0; rr < 4; ++rr) p[rr] = (_Float16)acc[i][j][rr];
                *(f16x4*)&S[hl * EPI_STRIDE + tl] = p;
            }
        __syncthreads();
        const int bi  = mtile >> 4;            // batch of this m-strip
        const int t0g = (mtile & 15) * 128;
        _Float16* vb = vT + (size_t)bi * HH * TT;
#pragma unroll
        for (int rr = 0; rr < 128; rr += 16) {
            int h = rr + (tid >> 4);
            int t = (tid & 15) * 8;
            f16x8 val = *(const f16x8*)&S[h * EPI_STRIDE + t];
            *(f16x8*)&vb[(size_t)(n0 + h) * TT + t0g + t] = val;
        }
    } else {
        // pass 1: hi tile staged [t_local][c_local], coalesced store
#pragma unroll
        for (int i = 0; i < 4; ++i)
#pragma unroll
            for (int j = 0; j < 4; ++j) {
                int tl = wr + i * 16 + quad * 4;
                int cl = wc + j * 16 + lrow;
#pragma unroll
                for (int rr = 0; rr < 4; ++rr)
                    S[(tl + rr) * EPI_STRIDE + cl] = (_Float16)acc[i][j][rr];
            }
        __syncthreads();
#pragma unroll
        for (int rr = 0; rr < 128; rr += 16) {
            int t = rr + (tid >> 4);
            int c = (tid & 15) * 8;
            f16x8 val = *(const f16x8*)&S[t * EPI_STRIDE + c];
            *(f16x8*)&Ph[(size_t)(m0 + t) * CC + n0 + c] = val;
        }
        // pass 2: lo tile
        __syncthreads();
#pragma unroll
        for (int i = 0; i < 4; ++i)
#pragma unroll
            for (int j = 0; j < 4; ++j) {
                int tl = wr + i * 16 + quad * 4;
                int cl = wc + j * 16 + lrow;
#pragma unroll
                for (int rr = 0; rr < 4; ++rr) {
                    float val = acc[i][j][rr];
                    _Float16 h = (_Float16)val;
                    S[(tl + rr) * EPI_STRIDE + cl] = (_Float16)(val - (float)h);
                }
            }
        __syncthreads();
#pragma unroll
        for (int rr = 0; rr < 128; rr += 16) {
            int t = rr + (tid >> 4);
            int c = (tid & 15) * 8;
            f16x8 val = *(const f16x8*)&S[t * EPI_STRIDE + c];
            *(f16x8*)&Pl[(size_t)(m0 + t) * CC + n0 + c] = val;
        }
    }
}

// ---------------- Kernel 3: wei = (P x^T)/32, lower-tri 128-tiles, 3-pass ----
// Compact 1-D grid: 136 tri-tiles x 8 batches; batch == XCD strip.
// Asymmetric-depth counted-vmcnt pipeline (A depth-3, B depth-2; 80KB).
__global__ __launch_bounds__(256, 2) void logits_kernel(
    const _Float16* __restrict__ Ph, const _Float16* __restrict__ Pl,
    const _Float16* __restrict__ xh, const _Float16* __restrict__ xl,
    float* __restrict__ wei)
{
    __shared__ _Float16 S[40960];   // A: 3 x 8192 @0; B: 2 x 8192 @24576

    const int id  = blockIdx.x;
    const int b   = id & 7;          // batch == XCD
    const int tri = id >> 3;         // 0..135, row-major lower triangle
    int tt = (int)((sqrtf(8.0f * (float)tri + 1.0f) - 1.0f) * 0.5f);
    while ((tt + 1) * (tt + 2) / 2 <= tri) ++tt;
    while (tt * (tt + 1) / 2 > tri) --tt;
    const int st = tri - tt * (tt + 1) / 2;

    const size_t base = (size_t)b * TT * CC;
    float* wb = wei + (size_t)b * TT * TT;
    const int m0 = tt * 128;
    const int n0 = st * 128;

    const int tid  = threadIdx.x;
    const int r0   = tid & 127;
    const int k0   = tid >> 7;
    const int wave = tid >> 6;
    const int lane = tid & 63;
    const int quad = lane >> 4;
    const int lrow = lane & 15;
    const int wr   = (wave >> 1) * 64;
    const int wc   = (wave & 1) * 64;

    const size_t ga = base + (size_t)(m0 + r0) * CC + k0 * 8;
    const size_t gb = base + (size_t)(n0 + r0) * CC + k0 * 8;
    const int lds0 = tid * 8, lds1 = (tid + 256) * 8;

    f32x4 acc[4][4] = {};

#define LG_A(kc_, sp_) do { \
    _Float16* Sb = S + (sp_) * 8192; \
    gld16(Ph + ga + (kc_),      &Sb[lds0]); \
    gld16(Ph + ga + (kc_) + 16, &Sb[lds1]); \
    gld16(Pl + ga + (kc_),      &Sb[4096 + lds0]); \
    gld16(Pl + ga + (kc_) + 16, &Sb[4096 + lds1]); \
} while (0)
#define LG_B(kc_, sp_) do { \
    _Float16* Sb = S + 24576 + (sp_) * 8192; \
    gld16(xh + gb + (kc_),      &Sb[lds0]); \
    gld16(xh + gb + (kc_) + 16, &Sb[lds1]); \
    gld16(xl + gb + (kc_),      &Sb[4096 + lds0]); \
    gld16(xl + gb + (kc_) + 16, &Sb[4096 + lds1]); \
} while (0)

    LG_A(0, 0);
    LG_B(0, 0);
    LG_A(32, 1);

    int sa = 0, sb = 0;
    for (int kc = 0; kc < CC; kc += 32) {
        asm volatile("s_waitcnt vmcnt(4)" ::: "memory");
        __builtin_amdgcn_s_barrier();
        __builtin_amdgcn_sched_barrier(0);

        int kb = kc + 32; if (kb > CC - 32) kb = CC - 32;
        LG_B(kb, sb ^ 1);
        int ka = kc + 64; if (ka > CC - 32) ka = CC - 32;
        int s2 = sa + 2; if (s2 >= 3) s2 -= 3;
        LG_A(ka, s2);

        const _Float16* Ah = S + sa * 8192;
        const _Float16* Al = Ah + 4096;
        const _Float16* Bh = S + 24576 + sb * 8192;
        const _Float16* Bl = Bh + 4096;

        f16x8 ahf[4], alf[4], bhf[4], blf[4];
#pragma unroll
        for (int i = 0; i < 4; ++i) {
            ahf[i] = *(const f16x8*)&Ah[(quad * 128 + wr + i * 16 + lrow) * 8];
            alf[i] = *(const f16x8*)&Al[(quad * 128 + wr + i * 16 + lrow) * 8];
            bhf[i] = *(const f16x8*)&Bh[(quad * 128 + wc + i * 16 + lrow) * 8];
            blf[i] = *(const f16x8*)&Bl[(quad * 128 + wc + i * 16 + lrow) * 8];
        }
#pragma unroll
        for (int i = 0; i < 4; ++i)
#pragma unroll
            for (int j = 0; j < 4; ++j) {
                acc[i][j] = __builtin_amdgcn_mfma_f32_16x16x32_f16(ahf[i], bhf[j], acc[i][j], 0, 0, 0);
                acc[i][j] = __builtin_amdgcn_mfma_f32_16x16x32_f16(ahf[i], blf[j], acc[i][j], 0, 0, 0);
                acc[i][j] = __builtin_amdgcn_mfma_f32_16x16x32_f16(alf[i], bhf[j], acc[i][j], 0, 0, 0);
            }

        ++sa; if (sa == 3) sa = 0;
        sb ^= 1;
    }

    // drain garbage prefetches before kernel end (LDS dealloc hazard)
    asm volatile("s_waitcnt vmcnt(0)" ::: "memory");

    const float scale = 0.03125f;   // 1024^-0.5
#pragma unroll
    for (int i = 0; i < 4; ++i)
#pragma unroll
        for (int j = 0; j < 4; ++j)
#pragma unroll
            for (int r = 0; r < 4; ++r) {
                int rr = wr + i * 16 + quad * 4 + r;
                int cc = wc + j * 16 + lrow;
                wb[(size_t)(m0 + rr) * TT + n0 + cc] = acc[i][j][r] * scale;
            }
}

// ---------------- Kernel 4: causal softmax; writes fp32 wei + f16 wei16 ------
__global__ __launch_bounds__(256) void softmax_kernel(
    float* __restrict__ wei, _Float16* __restrict__ wei16)
{
    const int t = blockIdx.x;
    const int b = blockIdx.y;
    float* row = wei + (size_t)b * TT * TT + (size_t)t * TT;
    _Float16* row16 = wei16 + (size_t)b * TT * TT + (size_t)t * TT;
    const int n = t + 1;
    const int tid = threadIdx.x;
    const int base = tid * 8;

    float vals[8];
    if (base < n) {
        float4 v0 = *(const float4*)&row[base];
        float4 v1 = *(const float4*)&row[base + 4];
        vals[0] = v0.x; vals[1] = v0.y; vals[2] = v0.z; vals[3] = v0.w;
        vals[4] = v1.x; vals[5] = v1.y; vals[6] = v1.z; vals[7] = v1.w;
    } else {
#pragma unroll
        for (int i = 0; i < 8; ++i) vals[i] = -INFINITY;
    }

    float mx = -INFINITY;
#pragma unroll
    for (int i = 0; i < 8; ++i) {
        if (base + i >= n) vals[i] = -INFINITY;
        mx = fmaxf(mx, vals[i]);
    }
#pragma unroll
    for (int off = 32; off > 0; off >>= 1)
        mx = fmaxf(mx, __shfl_down(mx, off));

    __shared__ float redm[4];
    __shared__ float reds[4];
    if ((tid & 63) == 0) redm[tid >> 6] = mx;
    __syncthreads();
    const float m = fmaxf(fmaxf(redm[0], redm[1]), fmaxf(redm[2], redm[3]));

    float sum = 0.f;
#pragma unroll
    for (int i = 0; i < 8; ++i) {
        vals[i] = __expf(vals[i] - m);
        sum += vals[i];
    }
#pragma unroll
    for (int off = 32; off > 0; off >>= 1)
        sum += __shfl_down(sum, off);
    if ((tid & 63) == 0) reds[tid >> 6] = sum;
    __syncthreads();
    const float inv = 1.0f / (reds[0] + reds[1] + reds[2] + reds[3]);

    f16x8 h;
#pragma unroll
    for (int i = 0; i < 8; ++i) {
        float w = vals[i] * inv;     // masked: exp(-inf)*inv = 0 exactly
        vals[i] = w;
        h[i] = (_Float16)w;
    }
    *(float4*)&row[base]     = make_float4(vals[0], vals[1], vals[2], vals[3]);
    *(float4*)&row[base + 4] = make_float4(vals[4], vals[5], vals[6], vals[7]);
    *(f16x8*)&row16[base]    = h;
}

// ---------------- Kernel 5: out = wei16 @ vT^T (NT, f16, causal K) -----------
// Compact 1-D grid: batch == XCD strip, heavy (large tt) tiles first.
// Depth-3 counted-vmcnt pipeline; 48KB LDS -> 3 blocks/CU.
__global__ __launch_bounds__(256, 3) void out_kernel(
    const _Float16* __restrict__ wei16, const _Float16* __restrict__ vT,
    float* __restrict__ out)
{
    __shared__ _Float16 S[24576];   // 3 slots x (Ah|Bh of 4096 f16) = 48KB

    const int id = blockIdx.x;
    const int b  = id & 7;          // batch == XCD
    const int r  = id >> 3;         // 0..127
    const int tt = 15 - (r >> 3);   // heavy tiles dispatched first
    const int nb = r & 7;

    const _Float16* wb = wei16 + (size_t)b * TT * TT;
    const _Float16* vb = vT    + (size_t)b * HH * TT;
    float*          ob = out   + (size_t)b * TT * HH;

    const int m0 = tt * 128;
    const int n0 = nb * 128;
    const int kend = (tt + 1) * 128;  // wei16==0 above diagonal

    const int tid  = threadIdx.x;
    const int r0   = tid & 127;
    const int k0   = tid >> 7;
    const int wave = tid >> 6;
    const int lane = tid & 63;
    const int quad = lane >> 4;
    const int lrow = lane & 15;
    const int wr   = (wave >> 1) * 64;
    const int wc   = (wave & 1) * 64;

    const size_t ga = (size_t)(m0 + r0) * TT + k0 * 8;
    const size_t gb = (size_t)(n0 + r0) * TT + k0 * 8;
    const int lds0 = tid * 8, lds1 = (tid + 256) * 8;

    f32x4 acc[4][4] = {};

#define OUT_STAGE(kc_, sp_) do { \
    _Float16* Sb = S + (sp_) * 8192; \
    gld16(wb + ga + (kc_),      &Sb[lds0]); \
    gld16(wb + ga + (kc_) + 16, &Sb[lds1]); \
    gld16(vb + gb + (kc_),      &Sb[4096 + lds0]); \
    gld16(vb + gb + (kc_) + 16, &Sb[4096 + lds1]); \
} while (0)

    OUT_STAGE(0, 0);
    OUT_STAGE(32, 1);

    int sl = 0;
    for (int kc = 0; kc < kend; kc += 32) {
        asm volatile("s_waitcnt vmcnt(4)" ::: "memory");
        __builtin_amdgcn_s_barrier();
        __builtin_amdgcn_sched_barrier(0);

        int kpre = kc + 64;
        if (kpre > kend - 32) kpre = kend - 32;
        int s2 = sl + 2; if (s2 >= 3) s2 -= 3;
        OUT_STAGE(kpre, s2);

        const _Float16* Ah = S + sl * 8192;
        const _Float16* Bh = Ah + 4096;

        f16x8 ahf[4], bhf[4];
#pragma unroll
        for (int i = 0; i < 4; ++i) {
            ahf[i] = *(const f16x8*)&Ah[(quad * 128 + wr + i * 16 + lrow) * 8];
            bhf[i] = *(const f16x8*)&Bh[(quad * 128 + wc + i * 16 + lrow) * 8];
        }
#pragma unroll
        for (int i = 0; i < 4; ++i)
#pragma unroll
            for (int j = 0; j < 4; ++j)
                acc[i][j] = __builtin_amdgcn_mfma_f32_16x16x32_f16(ahf[i], bhf[j], acc[i][j], 0, 0, 0);

        ++sl; if (sl == 3) sl = 0;
    }

    // drain garbage prefetches before kernel end (LDS dealloc hazard)
    asm volatile("s_waitcnt vmcnt(0)" ::: "memory");

#pragma unroll
    for (int i = 0; i < 4; ++i)
#pragma unroll
        for (int j = 0; j < 4; ++j)
#pragma unroll
            for (int r2 = 0; r2 < 4; ++r2) {
                int rr = wr + i * 16 + quad * 4 + r2;
                int cc = wc + j * 16 + lrow;
                ob[(size_t)(m0 + rr) * HH + n0 + cc] = acc[i][j][r2];
            }
}

extern "C" void kernel_launch(void* const* d_in, const int* in_sizes, int n_in,
                              void* d_out, int out_size, void* d_ws, size_t ws_size,
                              hipStream_t stream)
{
    const float* x  = (const float*)d_in[0];
    const float* Wk = (const float*)d_in[1];
    const float* Wq = (const float*)d_in[2];
    const float* Wv = (const float*)d_in[3];

    const size_t NX = (size_t)BT * CC;          // 16M
    const size_t NW = (size_t)HH * CC;          // 1M

    float* out = (float*)d_out;                 // [8,2048,1024] fp32
    float* wei = out + (size_t)BT * HH;         // [8,2048,2048] fp32

    // W-derived scratch in d_out's OUT region (64MB; dead before out_kernel)
    _Float16* WqTh = (_Float16*)out;            // [C,H]
    _Float16* WqTl = WqTh + NW;
    _Float16* WkTh = WqTl + NW;
    _Float16* WkTl = WkTh + NW;
    _Float16* Wvh  = WkTl + NW;                 // [H,C]
    _Float16* Wvl  = Wvh  + NW;                 // scratch (unused)
    _Float16* MTh  = Wvl  + NW;                 // [C,C] = M^T
    _Float16* MTl  = MTh  + NW;                 // total 16MB < 64MB

    // ws: 160MB = 5 x 32MB
    _Float16* xh = (_Float16*)d_ws;
    _Float16* xl = xh + NX;
    _Float16* Ph = xl + NX;
    _Float16* Pl = Ph + NX;
    _Float16* vT = Pl + NX;                     // [B][H][T]
    _Float16* wei16 = (_Float16*)d_ws;          // overlays xh/xl/Ph after logits

    split_kernel<<<dim3(NX / 1024), 256, 0, stream>>>(x, xh, xl, (int)NX);
    splitT_kernel<<<dim3(HH / 64, CC / 64), 256, 0, stream>>>(Wq, WqTh, WqTl);
    splitT_kernel<<<dim3(HH / 64, CC / 64), 256, 0, stream>>>(Wk, WkTh, WkTl);
    split_kernel<<<dim3(NW / 1024), 256, 0, stream>>>(Wv, Wvh, Wvl, (int)NW);

    mm_kernel<<<dim3(CC / 128, CC / 128), 256, 0, stream>>>(
        WqTh, WqTl, WkTh, WkTl, MTh, MTl);
    pv_kernel<<<dim3(2048), 256, 0, stream>>>(
        xh, xl, MTh, MTl, Wvh, Ph, Pl, vT);
    logits_kernel<<<dim3(136 * BB), 256, 0, stream>>>(
        Ph, Pl, xh, xl, wei);
    softmax_kernel<<<dim3(TT, BB), 256, 0, stream>>>(wei, wei16);
    out_kernel<<<dim3(128 * BB), 256, 0, stream>>>(wei16, vT, out);
}